// Round 3
// baseline (406.993 us; speedup 1.0000x reference)
//
#include <hip/hip_runtime.h>
#include <hip/hip_bf16.h>
#include <math.h>

typedef __bf16 bf16;
typedef __attribute__((ext_vector_type(8))) __bf16 bf16x8;
typedef __attribute__((ext_vector_type(4))) __bf16 bf16x4;
typedef __attribute__((ext_vector_type(4))) float f32x4;

constexpr int BM = 128, BN = 128, BK = 64;  // BK = two 32-k halves

enum { EPI_PLAIN = 0, EPI_GELU = 1, EPI_RES = 2, EPI_GATE = 3 };

__device__ __forceinline__ void async16(const void* g, void* l) {
  __builtin_amdgcn_global_load_lds(
      (const __attribute__((address_space(1))) void*)g,
      (__attribute__((address_space(3))) void*)l, 16, 0, 0);
}

// barrier draining LDS ops but NOT the global_load_lds queue (vmcnt counted).
__device__ __forceinline__ void bar_lgkm() {
  asm volatile("s_waitcnt lgkmcnt(0)\n\ts_barrier" ::: "memory");
}

#define WAIT_VM(n) asm volatile("s_waitcnt vmcnt(" #n ")" ::: "memory")

// ---------------------------------------------------------------------------
// bf16 GEMM, C = A[M,K] @ B[N,K]^T + epilogue.  128x128 tile, 4 waves.
// Round-3 change vs round-2 (which tied round-0 at 79us, all pipes <45%):
// amortize per-phase overhead -- BK=64 as TWO 32-k halves per phase:
//   - each half keeps the byte-identical [128][32] layout + XOR chunk
//     swizzle (HW-verified conflict-free; a single [128][64] row layout
//     would re-introduce >=4-way conflicts since 128B rows alias banks).
//   - one barrier-pair + one loop iteration per 32 MFMAs (was per 16).
//   - staging addresses are 4 pointers incremented by BK (no per-call
//     64-bit row*K recompute -> less VALU on the critical path).
//   - double-buffered, counted WAIT_VM(8): phase t+1's 8 loads/thread stay
//     in flight across both barriers; vmcnt(0) only at the tail.
// LDS = 2 buf x 2 half x (A 8KB + B 8KB) = 64 KB -> 2 blocks/CU.
// ---------------------------------------------------------------------------
template <typename CT, int EPI>
__global__ __launch_bounds__(256, 2) void gemm_bt_a(
    const bf16* __restrict__ A, const bf16* __restrict__ B, CT* __restrict__ C,
    const float* __restrict__ bias, const bf16* __restrict__ resid,
    const float* __restrict__ sup, const float* __restrict__ wsg,
    const float* __restrict__ bsg, int M, int N, int K) {
  __shared__ bf16 As[2][2][BM * 32];  // [buf][khalf][128 rows x 32 k]
  __shared__ bf16 Bs[2][2][BN * 32];

  const int tid = threadIdx.x;
  const int bm = blockIdx.x, bn = blockIdx.y;
  const int lane = tid & 63;
  const int wv = tid >> 6;
  const int wm = (wv >> 1) * 64, wn = (wv & 1) * 64;
  const int quad = lane >> 4, l16 = lane & 15;

  f32x4 acc[4][4];
#pragma unroll
  for (int i = 0; i < 4; i++)
#pragma unroll
    for (int j = 0; j < 4; j++) acc[i][j] = f32x4{0.f, 0.f, 0.f, 0.f};

  // staging: thread covers chunk (row = it*64 + srow, slot = tid&3) of each
  // 32-k half; global source slot pre-swizzled with the same involution the
  // reader uses (LDS dest stays linear for global_load_lds).
  const int srow = tid >> 2;
  const int sq8 = ((tid & 3) ^ ((srow >> 1) & 3)) * 8;  // +64 rows: parity class unchanged
  const int slot8 = (quad ^ ((l16 >> 1) & 3)) * 8;      // read-side swizzled 16B slot

  // incrementing global source pointers (rows srow and srow+64)
  const bf16* pa0 = A + (size_t)(bm * BM + srow) * K + sq8;
  const bf16* pa1 = pa0 + (size_t)64 * K;
  const bf16* pb0 = B + (size_t)(bn * BN + srow) * K + sq8;
  const bf16* pb1 = pb0 + (size_t)64 * K;
  // LDS dest bases: chunk index within a half = it*256 + tid (HW adds lane*16B)
  bf16* dA = &As[0][0][0] + wv * 512;  // + buf*8192 + h*4096 + it*2048
  bf16* dB = &Bs[0][0][0] + wv * 512;

  auto stg = [&](int buf) {
    bf16* a = dA + buf * 8192;
    bf16* b = dB + buf * 8192;
    async16(pa0, a);              // it0 h0
    async16(pa0 + 32, a + 4096);  // it0 h1
    async16(pa1, a + 2048);       // it1 h0
    async16(pa1 + 32, a + 6144);  // it1 h1
    async16(pb0, b);
    async16(pb0 + 32, b + 4096);
    async16(pb1, b + 2048);
    async16(pb1 + 32, b + 6144);
    pa0 += BK; pa1 += BK; pb0 += BK; pb1 += BK;
  };

  stg(0);  // prologue: phase 0 in flight (8 loads/thread)

  const int nt = K >> 6;
  for (int t = 0; t < nt; ++t) {
    const int cur = t & 1;
    if (t + 1 < nt) {
      stg(cur ^ 1);  // issue next phase first
      WAIT_VM(8);    // phase t landed; phase t+1's 8 stay in flight
    } else {
      WAIT_VM(0);
    }
    bar_lgkm();

    const bf16* a0 = &As[cur][0][0];
    const bf16* a1 = &As[cur][1][0];
    const bf16* b0 = &Bs[cur][0][0];
    const bf16* b1 = &Bs[cur][1][0];
    bf16x8 af0[4], af1[4], bf0[4], bf1[4];
#pragma unroll
    for (int i = 0; i < 4; i++) {
      const int ro = (wm + i * 16 + l16) * 32 + slot8;
      af0[i] = *(const bf16x8*)&a0[ro];
      af1[i] = *(const bf16x8*)&a1[ro];
    }
#pragma unroll
    for (int j = 0; j < 4; j++) {
      const int ro = (wn + j * 16 + l16) * 32 + slot8;
      bf0[j] = *(const bf16x8*)&b0[ro];
      bf1[j] = *(const bf16x8*)&b1[ro];
    }
#pragma unroll
    for (int i = 0; i < 4; i++)
#pragma unroll
      for (int j = 0; j < 4; j++) {
        acc[i][j] = __builtin_amdgcn_mfma_f32_16x16x32_bf16(af0[i], bf0[j], acc[i][j], 0, 0, 0);
        acc[i][j] = __builtin_amdgcn_mfma_f32_16x16x32_bf16(af1[i], bf1[j], acc[i][j], 0, 0, 0);
      }
    bar_lgkm();  // all waves done reading buf[cur] before next stg overwrites
  }

#pragma unroll
  for (int i = 0; i < 4; i++) {
    int row0 = bm * BM + wm + i * 16 + quad * 4;
#pragma unroll
    for (int j = 0; j < 4; j++) {
      int col = bn * BN + wn + j * 16 + l16;
#pragma unroll
      for (int r = 0; r < 4; r++) {
        int row = row0 + r;
        size_t idx = (size_t)row * N + col;
        float v = acc[i][j][r];
        if constexpr (EPI == EPI_PLAIN) {
          C[idx] = (CT)v;
        } else if constexpr (EPI == EPI_GELU) {
          v += bias[col];
          float gl = 0.5f * v * (1.0f + erff(v * 0.70710678118654752f));
          C[idx] = (CT)gl;
        } else if constexpr (EPI == EPI_RES) {
          v += bias[col] + (float)resid[idx];
          C[idx] = (CT)v;
        } else {  // EPI_GATE
          v += bias[col];
          float g1 = 1.0f / (1.0f + expf(-v));
          float z = sup[row] * wsg[col] + bsg[col];
          float g2 = 1.0f / (1.0f + expf(-z));
          C[idx] = (CT)(g1 * g2);
        }
      }
    }
  }
}

// ---------------- chunked parallel scan ----------------
constexpr int SC_CH = 32, SC_NCH = 16, SC_CW = 32;

__global__ __launch_bounds__(512) void scan2_kernel(const float* __restrict__ g,
                                                    const bf16* __restrict__ xt,
                                                    bf16* __restrict__ s, int T, int C) {
  __shared__ float lA[SC_NCH][SC_CW];
  __shared__ float lB[SC_NCH][SC_CW];
  __shared__ float lC[SC_NCH][SC_CW];
  const int cl = threadIdx.x & (SC_CW - 1);
  const int ch = threadIdx.x / SC_CW;
  const int c = blockIdx.x * SC_CW + cl;
  const int n = blockIdx.y;
  const size_t base = ((size_t)n * T + ch * SC_CH) * C + c;

  float a_arr[SC_CH], sl[SC_CH];
  float A = 1.f, B = 0.f;
#pragma unroll
  for (int t = 0; t < SC_CH; ++t) {
    size_t idx = base + (size_t)t * C;
    float gv = g[idx], xv = (float)xt[idx];
    float at = 1.0f - gv;
    a_arr[t] = at;
    B = at * B + gv * xv;
    sl[t] = B;
    A *= at;
  }
  lA[ch][cl] = A;
  lB[ch][cl] = B;
  __syncthreads();
  if (ch == 0) {
    float carry = 0.f;
#pragma unroll
    for (int j = 0; j < SC_NCH; ++j) {
      lC[j][cl] = carry;
      carry = lA[j][cl] * carry + lB[j][cl];
    }
  }
  __syncthreads();
  const float carry = lC[ch][cl];
  float P = 1.f;
#pragma unroll
  for (int t = 0; t < SC_CH; ++t) {
    P *= a_arr[t];
    s[base + (size_t)t * C] = (bf16)(sl[t] + P * carry);
  }
}

// ---------------- weight converts (fused 5-way, scalar) ----------------
__global__ __launch_bounds__(256) void cvt5_kernel(
    const float* s0, bf16* d0, int n0, const float* s1, bf16* d1, int n1,
    const float* s2, bf16* d2, int n2, const float* s3, bf16* d3, int n3,
    const float* s4, bf16* d4, int n4) {
  const float* s; bf16* d; int n;
  switch (blockIdx.y) {
    case 0: s = s0; d = d0; n = n0; break;
    case 1: s = s1; d = d1; n = n1; break;
    case 2: s = s2; d = d2; n = n2; break;
    case 3: s = s3; d = d3; n = n3; break;
    default: s = s4; d = d4; n = n4; break;
  }
  int i = blockIdx.x * 256 + threadIdx.x;
  if (i < n) d[i] = (bf16)s[i];
}

// ---------------- vectorized fp32 -> bf16 (x_seq), n % 4 == 0 ----------------
__global__ __launch_bounds__(256) void cvtx_kernel(const float* __restrict__ in,
                                                   bf16* __restrict__ out, int n4) {
  int i = blockIdx.x * 256 + threadIdx.x;
  if (i < n4) {
    f32x4 v = *(const f32x4*)(in + (size_t)i * 4);
    bf16x4 b;
    b[0] = (bf16)v[0]; b[1] = (bf16)v[1]; b[2] = (bf16)v[2]; b[3] = (bf16)v[3];
    *(bf16x4*)(out + (size_t)i * 4) = b;
  }
}

extern "C" void kernel_launch(void* const* d_in, const int* in_sizes, int n_in,
                              void* d_out, int out_size, void* d_ws, size_t ws_size,
                              hipStream_t stream) {
  const float* x_seq = (const float*)d_in[0];
  const float* sup = (const float*)d_in[1];
  const float* W_in = (const float*)d_in[2];
  const float* W_out = (const float*)d_in[3];
  const float* W_bg = (const float*)d_in[4];
  const float* b_bg = (const float*)d_in[5];
  const float* W_sg = (const float*)d_in[6];
  const float* b_sg = (const float*)d_in[7];
  const float* W_f1 = (const float*)d_in[8];
  const float* b_f1 = (const float*)d_in[9];
  const float* W_f2 = (const float*)d_in[10];
  const float* b_f2 = (const float*)d_in[11];

  const int Nb = 32, T = 512, C = 768, H = 1536;
  const int M = Nb * T;  // 16384

  char* ws = (char*)d_ws;
  size_t off = 0;
  auto alloc = [&](size_t bytes) {
    void* p = ws + off;
    off += (bytes + 255) & ~(size_t)255;
    return p;
  };
  bf16* Win_bf = (bf16*)alloc((size_t)C * C * 2);
  bf16* Wf1_bf = (bf16*)alloc((size_t)H * C * 2);
  bf16* Wf2_bf = (bf16*)alloc((size_t)C * H * 2);
  bf16* Wbg_bf = (bf16*)alloc((size_t)C * C * 2);
  bf16* Wout_bf = (bf16*)alloc((size_t)C * C * 2);
  bf16* xs_bf = (bf16*)alloc((size_t)M * C * 2);  // x_seq bf16
  bf16* x_bf = (bf16*)alloc((size_t)M * C * 2);   // x; reused as s after G3
  bf16* h_bf = (bf16*)alloc((size_t)M * H * 2);
  bf16* xt_bf = (bf16*)alloc((size_t)M * C * 2);
  float* g_f = (float*)alloc((size_t)M * C * 4);
  bf16* s_bf = x_bf;  // x dead after G3

  cvt5_kernel<<<dim3((H * C + 255) / 256, 5), 256, 0, stream>>>(
      W_in, Win_bf, C * C, W_f1, Wf1_bf, H * C, W_f2, Wf2_bf, C * H,
      W_bg, Wbg_bf, C * C, W_out, Wout_bf, C * C);
  cvtx_kernel<<<(M * C / 4 + 255) / 256, 256, 0, stream>>>(x_seq, xs_bf, M * C / 4);

  dim3 blk(256);
  // G1: x = x_seq @ W_in^T
  gemm_bt_a<bf16, EPI_PLAIN><<<dim3(M / BM, C / BN), blk, 0, stream>>>(
      xs_bf, Win_bf, x_bf, nullptr, nullptr, nullptr, nullptr, nullptr, M, C, C);
  // G2: h = gelu(x @ W_f1^T + b_f1)
  gemm_bt_a<bf16, EPI_GELU><<<dim3(M / BM, H / BN), blk, 0, stream>>>(
      x_bf, Wf1_bf, h_bf, b_f1, nullptr, nullptr, nullptr, nullptr, M, H, C);
  // G3: xt = x + h @ W_f2^T + b_f2
  gemm_bt_a<bf16, EPI_RES><<<dim3(M / BM, C / BN), blk, 0, stream>>>(
      h_bf, Wf2_bf, xt_bf, b_f2, x_bf, nullptr, nullptr, nullptr, M, C, H);
  // G4: g = sigmoid(xt @ W_bg^T + b_bg) * sigmoid(sup*W_sg + b_sg)  (fp32 out)
  gemm_bt_a<float, EPI_GATE><<<dim3(M / BM, C / BN), blk, 0, stream>>>(
      xt_bf, Wbg_bf, g_f, b_bg, nullptr, sup, W_sg, b_sg, M, C, C);
  // scan
  scan2_kernel<<<dim3(C / SC_CW, Nb), dim3(SC_CW * SC_NCH), 0, stream>>>(
      g_f, xt_bf, s_bf, T, C);
  // G6: out = s @ W_out^T (fp32 out)
  gemm_bt_a<float, EPI_PLAIN><<<dim3(M / BM, C / BN), blk, 0, stream>>>(
      s_bf, Wout_bf, (float*)d_out, nullptr, nullptr, nullptr, nullptr, nullptr, M, C, C);
}

// Round 4
// 378.931 us; speedup vs baseline: 1.0741x; 1.0741x over previous
//
#include <hip/hip_runtime.h>
#include <hip/hip_bf16.h>
#include <math.h>

typedef __bf16 bf16;
typedef __attribute__((ext_vector_type(8))) __bf16 bf16x8;
typedef __attribute__((ext_vector_type(4))) __bf16 bf16x4;
typedef __attribute__((ext_vector_type(4))) float f32x4;

constexpr int BM = 128, BN = 128, BK = 32;

enum { EPI_PLAIN = 0, EPI_GELU = 1, EPI_RES = 2, EPI_GATE = 3 };

__device__ __forceinline__ void async16(const void* g, void* l) {
  __builtin_amdgcn_global_load_lds(
      (const __attribute__((address_space(1))) void*)g,
      (__attribute__((address_space(3))) void*)l, 16, 0, 0);
}

// barrier draining LDS ops but NOT the global_load_lds queue (vmcnt counted).
__device__ __forceinline__ void bar_lgkm() {
  asm volatile("s_waitcnt lgkmcnt(0)\n\ts_barrier" ::: "memory");
}

#define WAIT_VM(n) asm volatile("s_waitcnt vmcnt(" #n ")" ::: "memory")

// ---------------------------------------------------------------------------
// bf16 GEMM, C = A[M,K] @ B[N,K]^T + epilogue.  128x128 tile.
// Round-4 changes vs round-2 (79us; all pipes <=45% => latency-bound at
// ~2.5 waves/SIMD):
//  (1) 8 waves per block (512 thr), wave tile 64x32 (2x4 wave grid):
//      guarantees 2 waves/SIMD per block; ~2.5 resident blocks -> ~5/SIMD.
//      acc shrinks to 8 f32x4 -> low VGPR; __launch_bounds__(512,4).
//  (2) XCD-chunked block remap (bijective; nwg%8==0 for all grids here):
//      consecutive blocks on one XCD share the same A-panel (196 KB, L2-
//      resident) and walk all bn; weight panels (<=2.4 MB) go L2-warm per
//      XCD. Staging becomes L2-hits instead of cross-XCD L3 traffic.
// Kept from round-2 (HW-verified): 32 KB double-buffer, counted WAIT_VM
// (never 0 mid-loop), XOR chunk swizzle both-sides (bank conflicts == 0).
// ---------------------------------------------------------------------------
template <typename CT, int EPI>
__global__ __launch_bounds__(512, 4) void gemm_bt_a(
    const bf16* __restrict__ A, const bf16* __restrict__ B, CT* __restrict__ C,
    const float* __restrict__ bias, const bf16* __restrict__ resid,
    const float* __restrict__ sup, const float* __restrict__ wsg,
    const float* __restrict__ bsg, int M, int N, int K) {
  __shared__ bf16 As[2][BM * BK];
  __shared__ bf16 Bs[2][BN * BK];

  const int tid = threadIdx.x;
  // XCD-chunked remap: wgid%8 = XCD (HW round-robin) -> give each XCD a
  // contiguous chunk; within a chunk bn walks fastest (A-panel reuse).
  const int nwg = gridDim.x;
  const int cpx = nwg >> 3;  // nwg % 8 == 0 for all grids used here
  const int wg = blockIdx.x;
  const int sw = (wg & 7) * cpx + (wg >> 3);
  const int ntn = N >> 7;  // N / BN
  const int bm = sw / ntn, bn = sw - bm * ntn;

  const int lane = tid & 63;
  const int wv = tid >> 6;
  const int wm = (wv >> 2) * 64, wn = (wv & 3) * 32;  // 2x4 wave grid
  const int quad = lane >> 4, l16 = lane & 15;

  f32x4 acc[4][2];
#pragma unroll
  for (int i = 0; i < 4; i++)
#pragma unroll
    for (int j = 0; j < 2; j++) acc[i][j] = f32x4{0.f, 0.f, 0.f, 0.f};

  // staging: thread t covers chunk t of each 8KB tile: row = t>>2, slot =
  // t&3 pre-swizzled with the reader's involution (LDS dest stays linear).
  const int srow = tid >> 2;
  const int sq8 = ((tid & 3) ^ ((srow >> 1) & 3)) * 8;
  const int slot8 = (quad ^ ((l16 >> 1) & 3)) * 8;  // read-side swizzled slot

  const bf16* pa = A + (size_t)(bm * BM + srow) * K + sq8;
  const bf16* pb = B + (size_t)(bn * BN + srow) * K + sq8;
  bf16* dA = &As[0][0] + wv * 512;  // wave-uniform base; HW adds lane*16B
  bf16* dB = &Bs[0][0] + wv * 512;

  auto stg = [&](int buf) {
    async16(pa, dA + buf * 4096);
    async16(pb, dB + buf * 4096);
    pa += BK;
    pb += BK;
  };

  stg(0);  // prologue: tile 0 in flight (2 loads/thread)

  const int nt = K / BK;
  for (int t = 0; t < nt; ++t) {
    const int cur = t & 1;
    if (t + 1 < nt) {
      stg(cur ^ 1);  // issue next tile first
      WAIT_VM(2);    // tile t landed; tile t+1's 2 loads stay in flight
    } else {
      WAIT_VM(0);
    }
    bar_lgkm();

    bf16x8 af[4], bfr[2];
#pragma unroll
    for (int i = 0; i < 4; i++)
      af[i] = *(const bf16x8*)&As[cur][(wm + i * 16 + l16) * BK + slot8];
#pragma unroll
    for (int j = 0; j < 2; j++)
      bfr[j] = *(const bf16x8*)&Bs[cur][(wn + j * 16 + l16) * BK + slot8];
#pragma unroll
    for (int i = 0; i < 4; i++)
#pragma unroll
      for (int j = 0; j < 2; j++)
        acc[i][j] = __builtin_amdgcn_mfma_f32_16x16x32_bf16(af[i], bfr[j], acc[i][j], 0, 0, 0);
    bar_lgkm();  // all waves done reading buf[cur] before next stg overwrites
  }

#pragma unroll
  for (int i = 0; i < 4; i++) {
    int row0 = bm * BM + wm + i * 16 + quad * 4;
#pragma unroll
    for (int j = 0; j < 2; j++) {
      int col = bn * BN + wn + j * 16 + l16;
#pragma unroll
      for (int r = 0; r < 4; r++) {
        int row = row0 + r;
        size_t idx = (size_t)row * N + col;
        float v = acc[i][j][r];
        if constexpr (EPI == EPI_PLAIN) {
          C[idx] = (CT)v;
        } else if constexpr (EPI == EPI_GELU) {
          v += bias[col];
          float gl = 0.5f * v * (1.0f + erff(v * 0.70710678118654752f));
          C[idx] = (CT)gl;
        } else if constexpr (EPI == EPI_RES) {
          v += bias[col] + (float)resid[idx];
          C[idx] = (CT)v;
        } else {  // EPI_GATE
          v += bias[col];
          float g1 = 1.0f / (1.0f + expf(-v));
          float z = sup[row] * wsg[col] + bsg[col];
          float g2 = 1.0f / (1.0f + expf(-z));
          C[idx] = (CT)(g1 * g2);
        }
      }
    }
  }
}

// ---------------- chunked parallel scan ----------------
constexpr int SC_CH = 32, SC_NCH = 16, SC_CW = 32;

__global__ __launch_bounds__(512) void scan2_kernel(const float* __restrict__ g,
                                                    const bf16* __restrict__ xt,
                                                    bf16* __restrict__ s, int T, int C) {
  __shared__ float lA[SC_NCH][SC_CW];
  __shared__ float lB[SC_NCH][SC_CW];
  __shared__ float lC[SC_NCH][SC_CW];
  const int cl = threadIdx.x & (SC_CW - 1);
  const int ch = threadIdx.x / SC_CW;
  const int c = blockIdx.x * SC_CW + cl;
  const int n = blockIdx.y;
  const size_t base = ((size_t)n * T + ch * SC_CH) * C + c;

  float a_arr[SC_CH], sl[SC_CH];
  float A = 1.f, B = 0.f;
#pragma unroll
  for (int t = 0; t < SC_CH; ++t) {
    size_t idx = base + (size_t)t * C;
    float gv = g[idx], xv = (float)xt[idx];
    float at = 1.0f - gv;
    a_arr[t] = at;
    B = at * B + gv * xv;
    sl[t] = B;
    A *= at;
  }
  lA[ch][cl] = A;
  lB[ch][cl] = B;
  __syncthreads();
  if (ch == 0) {
    float carry = 0.f;
#pragma unroll
    for (int j = 0; j < SC_NCH; ++j) {
      lC[j][cl] = carry;
      carry = lA[j][cl] * carry + lB[j][cl];
    }
  }
  __syncthreads();
  const float carry = lC[ch][cl];
  float P = 1.f;
#pragma unroll
  for (int t = 0; t < SC_CH; ++t) {
    P *= a_arr[t];
    s[base + (size_t)t * C] = (bf16)(sl[t] + P * carry);
  }
}

// ---------------- weight converts (fused 5-way, scalar) ----------------
__global__ __launch_bounds__(256) void cvt5_kernel(
    const float* s0, bf16* d0, int n0, const float* s1, bf16* d1, int n1,
    const float* s2, bf16* d2, int n2, const float* s3, bf16* d3, int n3,
    const float* s4, bf16* d4, int n4) {
  const float* s; bf16* d; int n;
  switch (blockIdx.y) {
    case 0: s = s0; d = d0; n = n0; break;
    case 1: s = s1; d = d1; n = n1; break;
    case 2: s = s2; d = d2; n = n2; break;
    case 3: s = s3; d = d3; n = n3; break;
    default: s = s4; d = d4; n = n4; break;
  }
  int i = blockIdx.x * 256 + threadIdx.x;
  if (i < n) d[i] = (bf16)s[i];
}

// ---------------- vectorized fp32 -> bf16 (x_seq), n % 4 == 0 ----------------
__global__ __launch_bounds__(256) void cvtx_kernel(const float* __restrict__ in,
                                                   bf16* __restrict__ out, int n4) {
  int i = blockIdx.x * 256 + threadIdx.x;
  if (i < n4) {
    f32x4 v = *(const f32x4*)(in + (size_t)i * 4);
    bf16x4 b;
    b[0] = (bf16)v[0]; b[1] = (bf16)v[1]; b[2] = (bf16)v[2]; b[3] = (bf16)v[3];
    *(bf16x4*)(out + (size_t)i * 4) = b;
  }
}

extern "C" void kernel_launch(void* const* d_in, const int* in_sizes, int n_in,
                              void* d_out, int out_size, void* d_ws, size_t ws_size,
                              hipStream_t stream) {
  const float* x_seq = (const float*)d_in[0];
  const float* sup = (const float*)d_in[1];
  const float* W_in = (const float*)d_in[2];
  const float* W_out = (const float*)d_in[3];
  const float* W_bg = (const float*)d_in[4];
  const float* b_bg = (const float*)d_in[5];
  const float* W_sg = (const float*)d_in[6];
  const float* b_sg = (const float*)d_in[7];
  const float* W_f1 = (const float*)d_in[8];
  const float* b_f1 = (const float*)d_in[9];
  const float* W_f2 = (const float*)d_in[10];
  const float* b_f2 = (const float*)d_in[11];

  const int Nb = 32, T = 512, C = 768, H = 1536;
  const int M = Nb * T;  // 16384

  char* ws = (char*)d_ws;
  size_t off = 0;
  auto alloc = [&](size_t bytes) {
    void* p = ws + off;
    off += (bytes + 255) & ~(size_t)255;
    return p;
  };
  bf16* Win_bf = (bf16*)alloc((size_t)C * C * 2);
  bf16* Wf1_bf = (bf16*)alloc((size_t)H * C * 2);
  bf16* Wf2_bf = (bf16*)alloc((size_t)C * H * 2);
  bf16* Wbg_bf = (bf16*)alloc((size_t)C * C * 2);
  bf16* Wout_bf = (bf16*)alloc((size_t)C * C * 2);
  bf16* xs_bf = (bf16*)alloc((size_t)M * C * 2);  // x_seq bf16
  bf16* x_bf = (bf16*)alloc((size_t)M * C * 2);   // x; reused as s after G3
  bf16* h_bf = (bf16*)alloc((size_t)M * H * 2);
  bf16* xt_bf = (bf16*)alloc((size_t)M * C * 2);
  float* g_f = (float*)alloc((size_t)M * C * 4);
  bf16* s_bf = x_bf;  // x dead after G3

  cvt5_kernel<<<dim3((H * C + 255) / 256, 5), 256, 0, stream>>>(
      W_in, Win_bf, C * C, W_f1, Wf1_bf, H * C, W_f2, Wf2_bf, C * H,
      W_bg, Wbg_bf, C * C, W_out, Wout_bf, C * C);
  cvtx_kernel<<<(M * C / 4 + 255) / 256, 256, 0, stream>>>(x_seq, xs_bf, M * C / 4);

  dim3 blk(512);
  // 1D grids (XCD remap in-kernel); nwg % 8 == 0 for all of these.
  // G1: x = x_seq @ W_in^T
  gemm_bt_a<bf16, EPI_PLAIN><<<dim3((M / BM) * (C / BN)), blk, 0, stream>>>(
      xs_bf, Win_bf, x_bf, nullptr, nullptr, nullptr, nullptr, nullptr, M, C, C);
  // G2: h = gelu(x @ W_f1^T + b_f1)
  gemm_bt_a<bf16, EPI_GELU><<<dim3((M / BM) * (H / BN)), blk, 0, stream>>>(
      x_bf, Wf1_bf, h_bf, b_f1, nullptr, nullptr, nullptr, nullptr, M, H, C);
  // G3: xt = x + h @ W_f2^T + b_f2
  gemm_bt_a<bf16, EPI_RES><<<dim3((M / BM) * (C / BN)), blk, 0, stream>>>(
      h_bf, Wf2_bf, xt_bf, b_f2, x_bf, nullptr, nullptr, nullptr, M, C, H);
  // G4: g = sigmoid(xt @ W_bg^T + b_bg) * sigmoid(sup*W_sg + b_sg)  (fp32 out)
  gemm_bt_a<float, EPI_GATE><<<dim3((M / BM) * (C / BN)), blk, 0, stream>>>(
      xt_bf, Wbg_bf, g_f, b_bg, nullptr, sup, W_sg, b_sg, M, C, C);
  // scan
  scan2_kernel<<<dim3(C / SC_CW, Nb), dim3(SC_CW * SC_NCH), 0, stream>>>(
      g_f, xt_bf, s_bf, T, C);
  // G6: out = s @ W_out^T (fp32 out)
  gemm_bt_a<float, EPI_PLAIN><<<dim3((M / BM) * (C / BN)), blk, 0, stream>>>(
      s_bf, Wout_bf, (float*)d_out, nullptr, nullptr, nullptr, nullptr, nullptr, M, C, C);
}